// Round 7
// baseline (241.526 us; speedup 1.0000x reference)
//
#include <hip/hip_runtime.h>
#include <stdint.h>

#define NN 50000
#define NB 196              // ceil(NN/256)
#define NEG_SLOPE 0.2f
#define WTS 136             // padded W^T row stride (u16)

// output layout (element offsets)
#define IXZ_OFF    (NN * 64)
#define SKL_OFF    (NN * 64 + NN)
#define MEAN_OFF   (NN * 64 + NN + 1)
#define STD_OFF    (MEAN_OFF + NN * 64)

typedef unsigned int u32;
typedef unsigned short u16;
typedef __attribute__((ext_vector_type(8))) short short8;
typedef __attribute__((ext_vector_type(4))) float f32x4;

__device__ __forceinline__ float bf2f(u16 s) { return __uint_as_float(((u32)s) << 16); }
__device__ __forceinline__ u16 f2bf(float f) {
    u32 u = __float_as_uint(f);
    u += 0x7FFFu + ((u >> 16) & 1u);   // RNE
    return (u16)(u >> 16);
}
__device__ __forceinline__ float lo16(u32 u) { return __uint_as_float(u << 16); }
__device__ __forceinline__ float hi16(u32 u) { return __uint_as_float(u & 0xFFFF0000u); }
__device__ __forceinline__ float softplusf(float x) {
    return fmaxf(x, 0.f) + log1pf(expf(-fabsf(x)));
}
__device__ __forceinline__ void stout(void* o, long long idx, float v, bool f32) {
    if (f32) ((float*)o)[idx] = v;
    else     ((u16*)o)[idx]   = f2bf(v);
}
__device__ __forceinline__ int wscan_incl(int v, int lane) {
#pragma unroll
    for (int off = 1; off < 64; off <<= 1) {
        int u = __shfl_up(v, off);
        if (lane >= off) v += u;
    }
    return v;
}

// ---------------------------------------------------------------------------
// k_wt: dtype-detect -> flag, zero counts+cursor, W -> padded W^T image (bf16)
// ---------------------------------------------------------------------------
__global__ __launch_bounds__(256) void k_wt(const u32* __restrict__ xw,
                                            const void* __restrict__ wv_,
                                            int* __restrict__ flag,
                                            u16* __restrict__ wtg,
                                            int* __restrict__ zbase)
{
    __shared__ int lflag;
    const int t = threadIdx.x;
    if (t < 64) {
        u32 wrd = xw[t];
        u32 e = (wrd >> 7) & 0xFF;
        bool plaus = (e >= 0x60 && e <= 0x85);
        unsigned long long b = __ballot(plaus);
        if (t == 0) {
            int f = (__popcll(b) < 32) ? 1 : 0;
            lflag = f;
            if (blockIdx.x == 0) flag[0] = f;
        }
    }
    __syncthreads();
    const bool f32 = lflag != 0;

    const int gid = blockIdx.x * 256 + t;
    for (int i = gid; i < 2 * NN; i += 8 * 256) zbase[i] = 0;

    const int k = blockIdx.x * 16 + (t >> 4);
    const int cq = t & 15;
    u16 v[8];
    if (f32) {
        const float* w = (const float*)wv_;
        float4 a = *(const float4*)(w + k * 128 + cq * 8);
        float4 b = *(const float4*)(w + k * 128 + cq * 8 + 4);
        v[0] = f2bf(a.x); v[1] = f2bf(a.y); v[2] = f2bf(a.z); v[3] = f2bf(a.w);
        v[4] = f2bf(b.x); v[5] = f2bf(b.y); v[6] = f2bf(b.z); v[7] = f2bf(b.w);
    } else {
        const u16* w = (const u16*)wv_;
        uint4 u = *(const uint4*)(w + k * 128 + cq * 8);
        v[0] = (u16)(u.x & 0xFFFF); v[1] = (u16)(u.x >> 16);
        v[2] = (u16)(u.y & 0xFFFF); v[3] = (u16)(u.y >> 16);
        v[4] = (u16)(u.z & 0xFFFF); v[5] = (u16)(u.z >> 16);
        v[6] = (u16)(u.w & 0xFFFF); v[7] = (u16)(u.w >> 16);
    }
#pragma unroll
    for (int j = 0; j < 8; j++)
        wtg[(cq * 8 + j) * WTS + k] = v[j];
}

// ---------------------------------------------------------------------------
// MFMA GEMM: h = x @ W. Wave = 16 nodes x 128 ch, 32x mfma_f32_16x16x32_bf16.
// Tail: grid-stride dst-degree count (overlaps other blocks' MFMA).
// ---------------------------------------------------------------------------
__global__ __launch_bounds__(256) void k_gemm(
    const void* __restrict__ xv, const u16* __restrict__ wtg,
    const void* __restrict__ attv, const int* __restrict__ flag,
    u16* __restrict__ hb, float* __restrict__ ai, float* __restrict__ aj,
    const int* __restrict__ dst, int* __restrict__ counts, int E)
{
    __shared__ __align__(16) u16 ls[128 * WTS];   // 34816 B
    const int tid = threadIdx.x;
    const bool f32 = flag[0] != 0;

    {
        uint4* d = (uint4*)ls;
        const uint4* s = (const uint4*)wtg;
        for (int i = tid; i < 128 * WTS / 8; i += 256) d[i] = s[i];
    }

    const int w = tid >> 6, L = tid & 63;
    const int q = L >> 4, c15 = L & 15;
    const int nb16 = blockIdx.x * 64 + w * 16;

    short8 afr[4];
    {
        int nrow = nb16 + c15; if (nrow > NN - 1) nrow = NN - 1;
        if (f32) {
            const float* xp = (const float*)xv + (size_t)nrow * 128 + q * 8;
#pragma unroll
            for (int ks = 0; ks < 4; ks++) {
                float4 a = *(const float4*)(xp + ks * 32);
                float4 b = *(const float4*)(xp + ks * 32 + 4);
                union { short8 s; u16 e[8]; } u;
                u.e[0] = f2bf(a.x); u.e[1] = f2bf(a.y); u.e[2] = f2bf(a.z); u.e[3] = f2bf(a.w);
                u.e[4] = f2bf(b.x); u.e[5] = f2bf(b.y); u.e[6] = f2bf(b.z); u.e[7] = f2bf(b.w);
                afr[ks] = u.s;
            }
        } else {
            const u16* xp = (const u16*)xv + (size_t)nrow * 128 + q * 8;
#pragma unroll
            for (int ks = 0; ks < 4; ks++)
                afr[ks] = *(const short8*)(xp + ks * 32);
        }
    }
    __syncthreads();

    f32x4 acc[8];
#pragma unroll
    for (int t = 0; t < 8; t++) {
        acc[t] = (f32x4){0.f, 0.f, 0.f, 0.f};
        const u16* bp = ls + (16 * t + c15) * WTS + q * 8;
#pragma unroll
        for (int ks = 0; ks < 4; ks++) {
            short8 bfr = *(const short8*)(bp + ks * 32);
            acc[t] = __builtin_amdgcn_mfma_f32_16x16x32_bf16(afr[ks], bfr, acc[t], 0, 0, 0);
        }
    }

    float ati[8], atj[8];
#pragma unroll
    for (int t = 0; t < 8; t++) {
        int p = (t >> 1) * 64 + (t & 1) * 16 + c15;
        if (f32) {
            ati[t] = ((const float*)attv)[p];
            atj[t] = ((const float*)attv)[p + 32];
        } else {
            ati[t] = bf2f(((const u16*)attv)[p]);
            atj[t] = bf2f(((const u16*)attv)[p + 32]);
        }
    }
#pragma unroll
    for (int r = 0; r < 4; r++) {
        int node = nb16 + q * 4 + r;
#pragma unroll
        for (int h = 0; h < 4; h++) {
            float pi = acc[2 * h][r] * ati[2 * h] + acc[2 * h + 1][r] * ati[2 * h + 1];
            float pj = acc[2 * h][r] * atj[2 * h] + acc[2 * h + 1][r] * atj[2 * h + 1];
            pi += __shfl_xor(pi, 1); pj += __shfl_xor(pj, 1);
            pi += __shfl_xor(pi, 2); pj += __shfl_xor(pj, 2);
            pi += __shfl_xor(pi, 4); pj += __shfl_xor(pj, 4);
            pi += __shfl_xor(pi, 8); pj += __shfl_xor(pj, 8);
            if (c15 == 0 && node < NN) { ai[node * 4 + h] = pi; aj[node * 4 + h] = pj; }
        }
    }

    __syncthreads();
    u16* myls = ls + w * 16 * WTS;
#pragma unroll
    for (int t = 0; t < 8; t++)
#pragma unroll
        for (int r = 0; r < 4; r++)
            myls[(q * 4 + r) * WTS + 16 * t + c15] = f2bf(acc[t][r]);
#pragma unroll
    for (int v = 0; v < 4; v++) {
        int idx = v * 64 + L;
        int nrow = idx >> 4, c8 = idx & 15;
        int node = nb16 + nrow;
        if (node < NN)
            *(uint4*)(hb + (size_t)node * 128 + c8 * 8) =
                *(const uint4*)(myls + nrow * WTS + c8 * 8);
    }

    const int gid = blockIdx.x * 256 + tid;
    const int stride = gridDim.x * 256;
    for (int e = gid; e < E; e += stride)
        atomicAdd(&counts[dst[e]], 1);
}

// ---------------------------------------------------------------------------
// hierarchical scan (2 levels)
// ---------------------------------------------------------------------------
__global__ __launch_bounds__(256) void k_scan1(const int* __restrict__ counts,
                                               int* __restrict__ lexcl,
                                               int* __restrict__ blocksum)
{
    __shared__ int wsum[4];
    const int t = threadIdx.x, lane = t & 63, wv = t >> 6;
    const int i = blockIdx.x * 256 + t;
    int c = (i < NN) ? counts[i] : 0;
    int inc = wscan_incl(c, lane);
    if (lane == 63) wsum[wv] = inc;
    __syncthreads();
    int add = 0;
#pragma unroll
    for (int k = 0; k < 3; k++) if (k < wv) add += wsum[k];
    inc += add;
    if (i < NN) lexcl[i] = inc - c;
    if (t == 255) blocksum[blockIdx.x] = inc;
}

__global__ __launch_bounds__(256) void k_scan2(const int* __restrict__ blocksum,
                                               int* __restrict__ blockoff)
{
    __shared__ int wsum[4];
    const int t = threadIdx.x, lane = t & 63, wv = t >> 6;
    int c = (t < NB) ? blocksum[t] : 0;
    int inc = wscan_incl(c, lane);
    if (lane == 63) wsum[wv] = inc;
    __syncthreads();
    int add = 0;
#pragma unroll
    for (int k = 0; k < 3; k++) if (k < wv) add += wsum[k];
    inc += add;
    if (t < NB) blockoff[t] = inc - c;
}

// ---------------------------------------------------------------------------
// k_fill: CSR scatter + (if workspace allows) per-edge softmax numerators
// ev[head] = exp(leakyrelu(ai[dst]+aj[src])) as a float4 stream in CSR order.
// ---------------------------------------------------------------------------
__global__ __launch_bounds__(256) void k_fill(
    const int* __restrict__ src, const int* __restrict__ dst,
    const int* __restrict__ lexcl, const int* __restrict__ blockoff,
    int* __restrict__ cursor, const float4* __restrict__ ai4,
    const float4* __restrict__ aj4, int* __restrict__ perm_src,
    float4* __restrict__ pev, int E)
{
    int e = blockIdx.x * 256 + threadIdx.x;
    if (e >= E) return;
    int d = dst[e], s = src[e];
    int pos = blockoff[d >> 8] + lexcl[d] + atomicAdd(&cursor[d], 1);
    perm_src[pos] = s;
    if (pev) {
        float4 a = ai4[d], b = aj4[s];
        float4 ev;
        float x;
        x = a.x + b.x; x = x > 0.f ? x : NEG_SLOPE * x; ev.x = __expf(x);
        x = a.y + b.y; x = x > 0.f ? x : NEG_SLOPE * x; ev.y = __expf(x);
        x = a.z + b.z; x = x > 0.f ? x : NEG_SLOPE * x; ev.z = __expf(x);
        x = a.w + b.w; x = x > 0.f ? x : NEG_SLOPE * x; ev.w = __expf(x);
        pev[pos] = ev;
    }
}

// ---------------------------------------------------------------------------
// Aggregation + finalize: 8 threads/node, lane l -> channels 16l..16l+15,
// head = l>>1, (l&1)==0 -> mean half, ==1 -> std half.
// ev from stream (or in-loop fallback); prefetched perm_src, 2x unroll.
// ---------------------------------------------------------------------------
__global__ __launch_bounds__(256) void k_agg(
    const int* __restrict__ lexcl, const int* __restrict__ blockoff,
    const int* __restrict__ counts, const int* __restrict__ perm_src,
    const float* __restrict__ pev,
    const float* __restrict__ ai, const float* __restrict__ aj,
    const u16* __restrict__ hb, const void* __restrict__ biasv,
    const int* __restrict__ flag, void* __restrict__ outv)
{
    const int t = blockIdx.x * 256 + threadIdx.x;
    const int node = t >> 3;
    if (node >= NN) return;
    const bool f32 = flag[0] != 0;
    const int l = t & 7;
    const int head = l >> 1;
    const bool has_ev = (pev != nullptr);

    const int rs = blockoff[node >> 8] + lexcl[node];
    const int re = rs + counts[node];
    const float ain = has_ev ? 0.f : ai[node * 4 + head];
    const u16* hbl = hb + l * 16;

    float acc[16];
#pragma unroll
    for (int j = 0; j < 16; j++) acc[j] = 0.f;
    float dsum = 0.f;

    int i = rs;
    int s0 = (i < re) ? perm_src[i] : 0;
    int s1 = (i + 1 < re) ? perm_src[i + 1] : 0;
    while (i + 1 < re) {
        int s2 = (i + 2 < re) ? perm_src[i + 2] : 0;
        int s3 = (i + 3 < re) ? perm_src[i + 3] : 0;
        float e0, e1;
        if (has_ev) {
            e0 = pev[(size_t)i * 4 + head];
            e1 = pev[(size_t)(i + 1) * 4 + head];
        } else {
            float x0 = aj[s0 * 4 + head] + ain; x0 = x0 > 0.f ? x0 : NEG_SLOPE * x0;
            float x1 = aj[s1 * 4 + head] + ain; x1 = x1 > 0.f ? x1 : NEG_SLOPE * x1;
            e0 = __expf(x0); e1 = __expf(x1);
        }
        const u16* h0 = hbl + (size_t)s0 * 128;
        const u16* h1 = hbl + (size_t)s1 * 128;
        uint4 A0 = *(const uint4*)h0, B0 = *(const uint4*)(h0 + 8);
        uint4 A1 = *(const uint4*)h1, B1 = *(const uint4*)(h1 + 8);
        dsum += e0 + e1;
        acc[0]  += e0 * lo16(A0.x) + e1 * lo16(A1.x);
        acc[1]  += e0 * hi16(A0.x) + e1 * hi16(A1.x);
        acc[2]  += e0 * lo16(A0.y) + e1 * lo16(A1.y);
        acc[3]  += e0 * hi16(A0.y) + e1 * hi16(A1.y);
        acc[4]  += e0 * lo16(A0.z) + e1 * lo16(A1.z);
        acc[5]  += e0 * hi16(A0.z) + e1 * hi16(A1.z);
        acc[6]  += e0 * lo16(A0.w) + e1 * lo16(A1.w);
        acc[7]  += e0 * hi16(A0.w) + e1 * hi16(A1.w);
        acc[8]  += e0 * lo16(B0.x) + e1 * lo16(B1.x);
        acc[9]  += e0 * hi16(B0.x) + e1 * hi16(B1.x);
        acc[10] += e0 * lo16(B0.y) + e1 * lo16(B1.y);
        acc[11] += e0 * hi16(B0.y) + e1 * hi16(B1.y);
        acc[12] += e0 * lo16(B0.z) + e1 * lo16(B1.z);
        acc[13] += e0 * hi16(B0.z) + e1 * hi16(B1.z);
        acc[14] += e0 * lo16(B0.w) + e1 * lo16(B1.w);
        acc[15] += e0 * hi16(B0.w) + e1 * hi16(B1.w);
        i += 2; s0 = s2; s1 = s3;
    }
    if (i < re) {
        float e0;
        if (has_ev) e0 = pev[(size_t)i * 4 + head];
        else {
            float x0 = aj[s0 * 4 + head] + ain; x0 = x0 > 0.f ? x0 : NEG_SLOPE * x0;
            e0 = __expf(x0);
        }
        const u16* h0 = hbl + (size_t)s0 * 128;
        uint4 A0 = *(const uint4*)h0, B0 = *(const uint4*)(h0 + 8);
        dsum += e0;
        acc[0]  += e0 * lo16(A0.x); acc[1]  += e0 * hi16(A0.x);
        acc[2]  += e0 * lo16(A0.y); acc[3]  += e0 * hi16(A0.y);
        acc[4]  += e0 * lo16(A0.z); acc[5]  += e0 * hi16(A0.z);
        acc[6]  += e0 * lo16(A0.w); acc[7]  += e0 * hi16(A0.w);
        acc[8]  += e0 * lo16(B0.x); acc[9]  += e0 * hi16(B0.x);
        acc[10] += e0 * lo16(B0.y); acc[11] += e0 * hi16(B0.y);
        acc[12] += e0 * lo16(B0.z); acc[13] += e0 * hi16(B0.z);
        acc[14] += e0 * lo16(B0.w); acc[15] += e0 * hi16(B0.w);
    }

    const float inv = 1.f / (dsum + 1e-16f);
    float v[16];
    if (f32) {
        const float* bias = (const float*)biasv;
#pragma unroll
        for (int j = 0; j < 16; j++) v[j] = acc[j] * inv + bias[16 * l + j];
    } else {
        const u16* bias = (const u16*)biasv;
#pragma unroll
        for (int j = 0; j < 16; j++) v[j] = acc[j] * inv + bf2f(bias[16 * l + j]);
    }

    float part = 0.f;
    if ((l & 1) == 0) {   // mean half of this head
        long long o = (long long)node * 64 + head * 16;
#pragma unroll
        for (int j = 0; j < 16; j++) {
            part += 0.5f * v[j] * v[j];
            stout(outv, o + j, v[j], f32);
            stout(outv, (long long)MEAN_OFF + o + j, v[j], f32);
        }
    } else {              // std half
        long long os = (long long)STD_OFF + (long long)node * 64 + head * 16;
#pragma unroll
        for (int j = 0; j < 16; j++) {
            float s = softplusf(v[j] - 5.f) + 1e-10f;
            part += -logf(s) + 0.5f * s * s - 0.5f;
            stout(outv, os + j, s, f32);
        }
    }
    part += __shfl_xor(part, 1);
    part += __shfl_xor(part, 2);
    part += __shfl_xor(part, 4);
    if (l == 0) stout(outv, (long long)IXZ_OFF + node, part * 0.25f, f32);
    if (t == 0) stout(outv, (long long)SKL_OFF, 0.f, f32);
}

// ---------------------------------------------------------------------------
extern "C" void kernel_launch(void* const* d_in, const int* in_sizes, int n_in,
                              void* d_out, int out_size, void* d_ws, size_t ws_size,
                              hipStream_t stream)
{
    const void* x    = d_in[0];
    const int*  ei   = (const int*)d_in[1];
    const void* w    = d_in[2];
    const void* att  = d_in[3];
    const void* bias = d_in[4];

    const int E = in_sizes[1] / 2;
    const int* src = ei;
    const int* dst = ei + E;

    // workspace layout: hb | ai | aj | [pev] | perm_src | counts | cursor |
    //                   lexcl | blocksum | blockoff | flag | wtg
    u16*   hb = (u16*)d_ws;                           // NN*128 bf16
    float* ai = (float*)(hb + (size_t)NN * 128);
    float* aj = ai + NN * 4;
    size_t off_fixed = (size_t)NN * 128 * 2 + (size_t)NN * 4 * 4 * 2;  // 14.4 MB
    size_t pev_bytes = (size_t)E * 16;
    size_t rest = (size_t)E * 4 + (size_t)NN * 4 * 3 + NB * 4 * 2 + 4
                + 32 + 128 * WTS * 2;
    bool use_ev = ws_size >= off_fixed + pev_bytes + rest;

    float* pev      = use_ev ? (float*)((char*)d_ws + off_fixed) : nullptr;
    int*   perm_src = (int*)((char*)d_ws + off_fixed + (use_ev ? pev_bytes : 0));
    int*   counts   = perm_src + E;
    int*   cursor   = counts + NN;
    int*   lexcl    = cursor + NN;
    int*   blocksum = lexcl + NN;
    int*   blockoff = blocksum + NB;
    int*   flag     = blockoff + NB;
    u16*   wtg      = (u16*)(((uintptr_t)(flag + 1) + 15) & ~(uintptr_t)15);

    k_wt<<<8, 256, 0, stream>>>((const u32*)x, w, flag, wtg, counts);
    k_gemm<<<(NN + 63) / 64, 256, 0, stream>>>(x, wtg, att, flag, hb, ai, aj,
                                               dst, counts, E);
    k_scan1<<<NB, 256, 0, stream>>>(counts, lexcl, blocksum);
    k_scan2<<<1, 256, 0, stream>>>(blocksum, blockoff);
    k_fill<<<(E + 255) / 256, 256, 0, stream>>>(src, dst, lexcl, blockoff,
                                                cursor, (const float4*)ai,
                                                (const float4*)aj, perm_src,
                                                (float4*)pev, E);
    k_agg<<<(NN * 8 + 255) / 256, 256, 0, stream>>>(lexcl, blockoff, counts,
                                                    perm_src, pev, ai, aj, hb,
                                                    bias, flag, d_out);
}

// Round 8
// 221.740 us; speedup vs baseline: 1.0892x; 1.0892x over previous
//
#include <hip/hip_runtime.h>
#include <stdint.h>

#define NN 50000
#define NB 196              // ceil(NN/256)
#define NEG_SLOPE 0.2f
#define WTS 136             // padded W^T row stride (u16)

// output layout (element offsets)
#define IXZ_OFF    (NN * 64)
#define SKL_OFF    (NN * 64 + NN)
#define MEAN_OFF   (NN * 64 + NN + 1)
#define STD_OFF    (MEAN_OFF + NN * 64)

typedef unsigned int u32;
typedef unsigned short u16;
typedef __attribute__((ext_vector_type(8))) short short8;
typedef __attribute__((ext_vector_type(4))) float f32x4;

__device__ __forceinline__ float bf2f(u16 s) { return __uint_as_float(((u32)s) << 16); }
__device__ __forceinline__ u16 f2bf(float f) {
    u32 u = __float_as_uint(f);
    u += 0x7FFFu + ((u >> 16) & 1u);   // RNE
    return (u16)(u >> 16);
}
__device__ __forceinline__ float lo16(u32 u) { return __uint_as_float(u << 16); }
__device__ __forceinline__ float hi16(u32 u) { return __uint_as_float(u & 0xFFFF0000u); }
__device__ __forceinline__ float softplusf(float x) {
    return fmaxf(x, 0.f) + log1pf(expf(-fabsf(x)));
}
__device__ __forceinline__ void stout(void* o, long long idx, float v, bool f32) {
    if (f32) ((float*)o)[idx] = v;
    else     ((u16*)o)[idx]   = f2bf(v);
}
__device__ __forceinline__ int wscan_incl(int v, int lane) {
#pragma unroll
    for (int off = 1; off < 64; off <<= 1) {
        int u = __shfl_up(v, off);
        if (lane >= off) v += u;
    }
    return v;
}

// ---------------------------------------------------------------------------
// k_wt: dtype-detect -> flag, zero counts+cursor, W -> padded W^T image (bf16)
// ---------------------------------------------------------------------------
__global__ __launch_bounds__(256) void k_wt(const u32* __restrict__ xw,
                                            const void* __restrict__ wv_,
                                            int* __restrict__ flag,
                                            u16* __restrict__ wtg,
                                            int* __restrict__ zbase)
{
    __shared__ int lflag;
    const int t = threadIdx.x;
    if (t < 64) {
        u32 wrd = xw[t];
        u32 e = (wrd >> 7) & 0xFF;
        bool plaus = (e >= 0x60 && e <= 0x85);
        unsigned long long b = __ballot(plaus);
        if (t == 0) {
            int f = (__popcll(b) < 32) ? 1 : 0;
            lflag = f;
            if (blockIdx.x == 0) flag[0] = f;
        }
    }
    __syncthreads();
    const bool f32 = lflag != 0;

    const int gid = blockIdx.x * 256 + t;
    for (int i = gid; i < 2 * NN; i += 8 * 256) zbase[i] = 0;

    const int k = blockIdx.x * 16 + (t >> 4);
    const int cq = t & 15;
    u16 v[8];
    if (f32) {
        const float* w = (const float*)wv_;
        float4 a = *(const float4*)(w + k * 128 + cq * 8);
        float4 b = *(const float4*)(w + k * 128 + cq * 8 + 4);
        v[0] = f2bf(a.x); v[1] = f2bf(a.y); v[2] = f2bf(a.z); v[3] = f2bf(a.w);
        v[4] = f2bf(b.x); v[5] = f2bf(b.y); v[6] = f2bf(b.z); v[7] = f2bf(b.w);
    } else {
        const u16* w = (const u16*)wv_;
        uint4 u = *(const uint4*)(w + k * 128 + cq * 8);
        v[0] = (u16)(u.x & 0xFFFF); v[1] = (u16)(u.x >> 16);
        v[2] = (u16)(u.y & 0xFFFF); v[3] = (u16)(u.y >> 16);
        v[4] = (u16)(u.z & 0xFFFF); v[5] = (u16)(u.z >> 16);
        v[6] = (u16)(u.w & 0xFFFF); v[7] = (u16)(u.w >> 16);
    }
#pragma unroll
    for (int j = 0; j < 8; j++)
        wtg[(cq * 8 + j) * WTS + k] = v[j];
}

// ---------------------------------------------------------------------------
// MFMA GEMM: h = x @ W. Wave = 16 nodes x 128 ch, 32x mfma_f32_16x16x32_bf16.
// Tail: grid-stride dst-degree count (overlaps other blocks' MFMA).
// ---------------------------------------------------------------------------
__global__ __launch_bounds__(256) void k_gemm(
    const void* __restrict__ xv, const u16* __restrict__ wtg,
    const void* __restrict__ attv, const int* __restrict__ flag,
    u16* __restrict__ hb, float* __restrict__ ai, float* __restrict__ aj,
    const int* __restrict__ dst, int* __restrict__ counts, int E)
{
    __shared__ __align__(16) u16 ls[128 * WTS];   // 34816 B
    const int tid = threadIdx.x;
    const bool f32 = flag[0] != 0;

    {
        uint4* d = (uint4*)ls;
        const uint4* s = (const uint4*)wtg;
        for (int i = tid; i < 128 * WTS / 8; i += 256) d[i] = s[i];
    }

    const int w = tid >> 6, L = tid & 63;
    const int q = L >> 4, c15 = L & 15;
    const int nb16 = blockIdx.x * 64 + w * 16;

    short8 afr[4];
    {
        int nrow = nb16 + c15; if (nrow > NN - 1) nrow = NN - 1;
        if (f32) {
            const float* xp = (const float*)xv + (size_t)nrow * 128 + q * 8;
#pragma unroll
            for (int ks = 0; ks < 4; ks++) {
                float4 a = *(const float4*)(xp + ks * 32);
                float4 b = *(const float4*)(xp + ks * 32 + 4);
                union { short8 s; u16 e[8]; } u;
                u.e[0] = f2bf(a.x); u.e[1] = f2bf(a.y); u.e[2] = f2bf(a.z); u.e[3] = f2bf(a.w);
                u.e[4] = f2bf(b.x); u.e[5] = f2bf(b.y); u.e[6] = f2bf(b.z); u.e[7] = f2bf(b.w);
                afr[ks] = u.s;
            }
        } else {
            const u16* xp = (const u16*)xv + (size_t)nrow * 128 + q * 8;
#pragma unroll
            for (int ks = 0; ks < 4; ks++)
                afr[ks] = *(const short8*)(xp + ks * 32);
        }
    }
    __syncthreads();

    f32x4 acc[8];
#pragma unroll
    for (int t = 0; t < 8; t++) {
        acc[t] = (f32x4){0.f, 0.f, 0.f, 0.f};
        const u16* bp = ls + (16 * t + c15) * WTS + q * 8;
#pragma unroll
        for (int ks = 0; ks < 4; ks++) {
            short8 bfr = *(const short8*)(bp + ks * 32);
            acc[t] = __builtin_amdgcn_mfma_f32_16x16x32_bf16(afr[ks], bfr, acc[t], 0, 0, 0);
        }
    }

    float ati[8], atj[8];
#pragma unroll
    for (int t = 0; t < 8; t++) {
        int p = (t >> 1) * 64 + (t & 1) * 16 + c15;
        if (f32) {
            ati[t] = ((const float*)attv)[p];
            atj[t] = ((const float*)attv)[p + 32];
        } else {
            ati[t] = bf2f(((const u16*)attv)[p]);
            atj[t] = bf2f(((const u16*)attv)[p + 32]);
        }
    }
#pragma unroll
    for (int r = 0; r < 4; r++) {
        int node = nb16 + q * 4 + r;
#pragma unroll
        for (int h = 0; h < 4; h++) {
            float pi = acc[2 * h][r] * ati[2 * h] + acc[2 * h + 1][r] * ati[2 * h + 1];
            float pj = acc[2 * h][r] * atj[2 * h] + acc[2 * h + 1][r] * atj[2 * h + 1];
            pi += __shfl_xor(pi, 1); pj += __shfl_xor(pj, 1);
            pi += __shfl_xor(pi, 2); pj += __shfl_xor(pj, 2);
            pi += __shfl_xor(pi, 4); pj += __shfl_xor(pj, 4);
            pi += __shfl_xor(pi, 8); pj += __shfl_xor(pj, 8);
            if (c15 == 0 && node < NN) { ai[node * 4 + h] = pi; aj[node * 4 + h] = pj; }
        }
    }

    __syncthreads();
    u16* myls = ls + w * 16 * WTS;
#pragma unroll
    for (int t = 0; t < 8; t++)
#pragma unroll
        for (int r = 0; r < 4; r++)
            myls[(q * 4 + r) * WTS + 16 * t + c15] = f2bf(acc[t][r]);
#pragma unroll
    for (int v = 0; v < 4; v++) {
        int idx = v * 64 + L;
        int nrow = idx >> 4, c8 = idx & 15;
        int node = nb16 + nrow;
        if (node < NN)
            *(uint4*)(hb + (size_t)node * 128 + c8 * 8) =
                *(const uint4*)(myls + nrow * WTS + c8 * 8);
    }

    const int gid = blockIdx.x * 256 + tid;
    const int stride = gridDim.x * 256;
    for (int e = gid; e < E; e += stride)
        atomicAdd(&counts[dst[e]], 1);
}

// ---------------------------------------------------------------------------
// k_scan1: per-256-chunk exclusive prefix (lexcl) + chunk sums (blocksum)
// ---------------------------------------------------------------------------
__global__ __launch_bounds__(256) void k_scan1(const int* __restrict__ counts,
                                               int* __restrict__ lexcl,
                                               int* __restrict__ blocksum)
{
    __shared__ int wsum[4];
    const int t = threadIdx.x, lane = t & 63, wv = t >> 6;
    const int i = blockIdx.x * 256 + t;
    int c = (i < NN) ? counts[i] : 0;
    int inc = wscan_incl(c, lane);
    if (lane == 63) wsum[wv] = inc;
    __syncthreads();
    int add = 0;
#pragma unroll
    for (int k = 0; k < 3; k++) if (k < wv) add += wsum[k];
    inc += add;
    if (i < NN) lexcl[i] = inc - c;
    if (t == 255) blocksum[blockIdx.x] = inc;
}

// inline exclusive scan of the NB blocksums into sboff[256] (all 256 threads)
__device__ __forceinline__ void scan_blocksum(const int* __restrict__ blocksum,
                                              int* sboff, int* wsum)
{
    const int t = threadIdx.x, lane = t & 63, wv = t >> 6;
    int c = (t < NB) ? blocksum[t] : 0;
    int inc = wscan_incl(c, lane);
    if (lane == 63) wsum[wv] = inc;
    __syncthreads();
    int add = 0;
#pragma unroll
    for (int k = 0; k < 3; k++) if (k < wv) add += wsum[k];
    sboff[t] = inc + add - c;
    __syncthreads();
}

// ---------------------------------------------------------------------------
// k_fill: CSR scatter + per-edge softmax numerators (if workspace allows)
// ev[head] = exp(leakyrelu(ai[dst]+aj[src])) as float4 stream in CSR order.
// ---------------------------------------------------------------------------
__global__ __launch_bounds__(256) void k_fill(
    const int* __restrict__ src, const int* __restrict__ dst,
    const int* __restrict__ lexcl, const int* __restrict__ blocksum,
    int* __restrict__ cursor, const float4* __restrict__ ai4,
    const float4* __restrict__ aj4, int* __restrict__ perm_src,
    float4* __restrict__ pev, int E)
{
    __shared__ int sboff[256];
    __shared__ int wsum[4];
    scan_blocksum(blocksum, sboff, wsum);

    int e = blockIdx.x * 256 + threadIdx.x;
    if (e >= E) return;
    int d = dst[e], s = src[e];
    int pos = sboff[d >> 8] + lexcl[d] + atomicAdd(&cursor[d], 1);
    perm_src[pos] = s;
    if (pev) {
        float4 a = ai4[d], b = aj4[s];
        float4 ev;
        float x;
        x = a.x + b.x; x = x > 0.f ? x : NEG_SLOPE * x; ev.x = __expf(x);
        x = a.y + b.y; x = x > 0.f ? x : NEG_SLOPE * x; ev.y = __expf(x);
        x = a.z + b.z; x = x > 0.f ? x : NEG_SLOPE * x; ev.z = __expf(x);
        x = a.w + b.w; x = x > 0.f ? x : NEG_SLOPE * x; ev.w = __expf(x);
        pev[pos] = ev;
    }
}

// ---------------------------------------------------------------------------
// Aggregation + finalize: 16 threads/node (proven best occupancy shape),
// lane l -> channels 8l..8l+7, head = l>>2. ev from pev stream (fallback:
// recompute). Single-pass softmax (|alpha| <= ~8, exp safe in fp32).
// ---------------------------------------------------------------------------
__global__ __launch_bounds__(256) void k_agg(
    const int* __restrict__ lexcl, const int* __restrict__ blocksum,
    const int* __restrict__ counts, const int* __restrict__ perm_src,
    const float* __restrict__ pev,
    const float* __restrict__ ai, const float* __restrict__ aj,
    const u16* __restrict__ hb, const void* __restrict__ biasv,
    const int* __restrict__ flag, void* __restrict__ outv)
{
    __shared__ int sboff[256];
    __shared__ int wsum[4];
    scan_blocksum(blocksum, sboff, wsum);

    const int t = blockIdx.x * 256 + threadIdx.x;
    const int node = t >> 4;               // grid is exact: NN*16 threads
    const bool f32 = flag[0] != 0;
    const int l = t & 15;
    const int head = l >> 2;
    const int cc0 = (l & 3) << 3;
    const bool has_ev = (pev != nullptr);

    const int rs = sboff[(node >> 8) & 255] + lexcl[node];
    const int re = rs + counts[node];
    const float ain = has_ev ? 0.f : ai[node * 4 + head];
    const u16* hl8 = hb + l * 8;

    float dsum = 0.f;
    float a0 = 0.f, a1 = 0.f, a2 = 0.f, a3 = 0.f;
    float a4 = 0.f, a5 = 0.f, a6 = 0.f, a7 = 0.f;

    int i = rs;
    for (; i + 1 < re; i += 2) {
        int s0 = perm_src[i], s1 = perm_src[i + 1];
        float e0, e1;
        if (has_ev) {
            e0 = pev[(size_t)i * 4 + head];
            e1 = pev[(size_t)(i + 1) * 4 + head];
        } else {
            float x0 = aj[s0 * 4 + head] + ain;
            float x1 = aj[s1 * 4 + head] + ain;
            x0 = x0 > 0.f ? x0 : NEG_SLOPE * x0;
            x1 = x1 > 0.f ? x1 : NEG_SLOPE * x1;
            e0 = __expf(x0); e1 = __expf(x1);
        }
        uint4 h0 = *(const uint4*)(hl8 + (size_t)s0 * 128);
        uint4 h1 = *(const uint4*)(hl8 + (size_t)s1 * 128);
        dsum += e0 + e1;
        a0 += e0 * lo16(h0.x) + e1 * lo16(h1.x);
        a1 += e0 * hi16(h0.x) + e1 * hi16(h1.x);
        a2 += e0 * lo16(h0.y) + e1 * lo16(h1.y);
        a3 += e0 * hi16(h0.y) + e1 * hi16(h1.y);
        a4 += e0 * lo16(h0.z) + e1 * lo16(h1.z);
        a5 += e0 * hi16(h0.z) + e1 * hi16(h1.z);
        a6 += e0 * lo16(h0.w) + e1 * lo16(h1.w);
        a7 += e0 * hi16(h0.w) + e1 * hi16(h1.w);
    }
    if (i < re) {
        int s0 = perm_src[i];
        float e0;
        if (has_ev) e0 = pev[(size_t)i * 4 + head];
        else {
            float x0 = aj[s0 * 4 + head] + ain;
            x0 = x0 > 0.f ? x0 : NEG_SLOPE * x0;
            e0 = __expf(x0);
        }
        uint4 h0 = *(const uint4*)(hl8 + (size_t)s0 * 128);
        dsum += e0;
        a0 += e0 * lo16(h0.x); a1 += e0 * hi16(h0.x);
        a2 += e0 * lo16(h0.y); a3 += e0 * hi16(h0.y);
        a4 += e0 * lo16(h0.z); a5 += e0 * hi16(h0.z);
        a6 += e0 * lo16(h0.w); a7 += e0 * hi16(h0.w);
    }

    const float inv = 1.f / (dsum + 1e-16f);
    const int cb = head * 32 + cc0;
    float v[8];
    if (f32) {
        const float* bias = (const float*)biasv;
#pragma unroll
        for (int j = 0; j < 8; j++) v[j] = bias[cb + j];
    } else {
        const u16* bias = (const u16*)biasv;
#pragma unroll
        for (int j = 0; j < 8; j++) v[j] = bf2f(bias[cb + j]);
    }
    v[0] += a0 * inv; v[1] += a1 * inv; v[2] += a2 * inv; v[3] += a3 * inv;
    v[4] += a4 * inv; v[5] += a5 * inv; v[6] += a6 * inv; v[7] += a7 * inv;

    float part = 0.f;
    if (cc0 < 16) {     // mean channels
#pragma unroll
        for (int j = 0; j < 8; j++) part += 0.5f * v[j] * v[j];
        long long o = (long long)node * 64 + head * 16 + cc0;
#pragma unroll
        for (int j = 0; j < 8; j++) stout(outv, o + j, v[j], f32);
        long long om = (long long)MEAN_OFF + o;
#pragma unroll
        for (int j = 0; j < 8; j++) stout(outv, om + j, v[j], f32);
    } else {            // std channels
        long long os = (long long)STD_OFF + (long long)node * 64 + head * 16 + (cc0 - 16);
#pragma unroll
        for (int j = 0; j < 8; j++) {
            float s = softplusf(v[j] - 5.f) + 1e-10f;
            part += -logf(s) + 0.5f * s * s - 0.5f;
            stout(outv, os + j, s, f32);
        }
    }
    part += __shfl_xor(part, 1); part += __shfl_xor(part, 2);
    part += __shfl_xor(part, 4); part += __shfl_xor(part, 8);
    if (l == 0) stout(outv, (long long)IXZ_OFF + node, part * 0.25f, f32);
    if (t == 0) stout(outv, (long long)SKL_OFF, 0.f, f32);
}

// ---------------------------------------------------------------------------
extern "C" void kernel_launch(void* const* d_in, const int* in_sizes, int n_in,
                              void* d_out, int out_size, void* d_ws, size_t ws_size,
                              hipStream_t stream)
{
    const void* x    = d_in[0];
    const int*  ei   = (const int*)d_in[1];
    const void* w    = d_in[2];
    const void* att  = d_in[3];
    const void* bias = d_in[4];

    const int E = in_sizes[1] / 2;
    const int* src = ei;
    const int* dst = ei + E;

    // workspace: hb | ai | aj | [pev] | perm_src | counts | cursor | lexcl |
    //            blocksum | flag | wtg
    u16*   hb = (u16*)d_ws;                           // NN*128 bf16
    float* ai = (float*)(hb + (size_t)NN * 128);
    float* aj = ai + NN * 4;
    size_t off_fixed = (size_t)NN * 128 * 2 + (size_t)NN * 4 * 4 * 2;  // 14.4 MB
    size_t pev_bytes = (size_t)E * 16;
    size_t rest = (size_t)E * 4 + (size_t)NN * 4 * 3 + NB * 4 + 4
                + 32 + 128 * WTS * 2;
    bool use_ev = ws_size >= off_fixed + pev_bytes + rest;

    float* pev      = use_ev ? (float*)((char*)d_ws + off_fixed) : nullptr;
    int*   perm_src = (int*)((char*)d_ws + off_fixed + (use_ev ? pev_bytes : 0));
    int*   counts   = perm_src + E;
    int*   cursor   = counts + NN;
    int*   lexcl    = cursor + NN;
    int*   blocksum = lexcl + NN;
    int*   flag     = blocksum + NB;
    u16*   wtg      = (u16*)(((uintptr_t)(flag + 1) + 15) & ~(uintptr_t)15);

    k_wt<<<8, 256, 0, stream>>>((const u32*)x, w, flag, wtg, counts);
    k_gemm<<<(NN + 63) / 64, 256, 0, stream>>>(x, wtg, att, flag, hb, ai, aj,
                                               dst, counts, E);
    k_scan1<<<NB, 256, 0, stream>>>(counts, lexcl, blocksum);
    k_fill<<<(E + 255) / 256, 256, 0, stream>>>(src, dst, lexcl, blocksum,
                                                cursor, (const float4*)ai,
                                                (const float4*)aj, perm_src,
                                                (float4*)pev, E);
    k_agg<<<(NN * 16) / 256, 256, 0, stream>>>(lexcl, blocksum, counts,
                                               perm_src, pev, ai, aj, hb,
                                               bias, flag, d_out);
}